// Round 1
// baseline (584.106 us; speedup 1.0000x reference)
//
#include <hip/hip_runtime.h>
#include <hip/hip_bf16.h>

// BronxLayer fused implementation for MI355X (gfx950).
// N=3072 nodes, H=256 hidden, B=4 heads, HD=64 per-head.
//
// Pipeline:
//  k0_prep : transpose/convert weights to bf16 (WTcat [768][256], WvT [256][1024]), bias
//  k1_ln   : LayerNorm -> hn bf16 [3072][256]
//  k1b_tr  : hn -> hnT bf16 [256][3072]  (PV B-operand wants hnT)
//  k2_proj : hn @ [Wk|Wmu|Wls] (bf16 MFMA) -> kh/muh/lsh [mat][head][node][64] bf16
//            (scale HD^-0.5 folded into kh and b_k)
//  k3_fused: flash-style: S^T = muh@kh^T per head (MFMA), softplus/exp/KL elementwise,
//            unnormalized PV agg += a @ hn, denom += |a|, kl atomic. eps staged via LDS.
//  k35_norm: aggn = agg/denom -> bf16
//  k4_out  : aggn @ Wv (MFMA) + b_v -> elu -> + h0 -> d_out; writes kl scalar.
//
// Workspace use ~27.8 MB.

#define NN 3072
#define HH 256
#define NB 4
#define HD 64
constexpr int SP = 4;             // z-splits across workgroups
constexpr int ZCHUNK = NN / SP;   // 768
constexpr int ZT = 32;            // z per iteration
constexpr int NIT = ZCHUNK / ZT;  // 24

typedef __attribute__((ext_vector_type(8))) short bf16x8;
typedef __attribute__((ext_vector_type(4))) float f32x4;

static __device__ inline short f2bf(float f) {
    __hip_bfloat16 h = __float2bfloat16(f);
    return __builtin_bit_cast(short, h);
}

// ---------------- k0: weight prep ----------------
__global__ void k0_prep(const float* __restrict__ Wk, const float* __restrict__ Wmu,
                        const float* __restrict__ Wls, const float* __restrict__ bk,
                        const float* __restrict__ bmu, const float* __restrict__ bls,
                        const float* __restrict__ Wv,
                        short* __restrict__ WTcat, float* __restrict__ biascat,
                        short* __restrict__ WvT) {
    int idx = blockIdx.x * 256 + threadIdx.x;
    if (idx < 196608) {                       // WTcat[c'][yin], c' = mat*256 + b*64 + y
        int cp = idx >> 8, yin = idx & 255;
        int mat = cp >> 8, cc = cp & 255;
        int b = cc >> 6, y = cc & 63;
        int corig = y * 4 + b;
        const float* W = (mat == 0) ? Wk : (mat == 1 ? Wmu : Wls);
        float v = W[yin * 256 + corig];
        if (mat == 0) v *= 0.125f;            // fold HD^-0.5 into k
        WTcat[idx] = f2bf(v);
        return;
    }
    int j = idx - 196608;                     // WvT[n][k] = Wv[k][n]
    if (j < 262144) {
        int n = j >> 10, k = j & 1023;
        WvT[j] = f2bf(Wv[k * 256 + n]);
        return;
    }
    int b2 = j - 262144;
    if (b2 < 768) {
        int mat = b2 >> 8, cc = b2 & 255;
        int corig = (cc & 63) * 4 + (cc >> 6);
        const float* bb = (mat == 0) ? bk : (mat == 1 ? bmu : bls);
        float v = bb[corig];
        if (mat == 0) v *= 0.125f;
        biascat[b2] = v;
    }
}

// ---------------- k1: LayerNorm ----------------
__global__ void k1_ln(const float* __restrict__ h, const float* __restrict__ gamma,
                      const float* __restrict__ beta, short* __restrict__ hn) {
    int row = blockIdx.x, tid = threadIdx.x;
    float v = h[row * 256 + tid];
    float s = v, s2 = v * v;
    for (int off = 32; off; off >>= 1) {
        s += __shfl_xor(s, off);
        s2 += __shfl_xor(s2, off);
    }
    __shared__ float red[8];
    int w = tid >> 6, lane = tid & 63;
    if (!lane) { red[w] = s; red[4 + w] = s2; }
    __syncthreads();
    s = red[0] + red[1] + red[2] + red[3];
    s2 = red[4] + red[5] + red[6] + red[7];
    float mean = s * (1.f / 256.f);
    float var = s2 * (1.f / 256.f) - mean * mean;
    float rs = rsqrtf(var + 1e-5f);
    hn[row * 256 + tid] = f2bf((v - mean) * rs * gamma[tid] + beta[tid]);
}

// ---------------- k1b: transpose hn -> hnT ----------------
__global__ void k1b_tr(const short* __restrict__ hn, short* __restrict__ hnT) {
    __shared__ short t[64][257];
    int n0 = blockIdx.x * 64, tid = threadIdx.x;
    for (int i = 0; i < 64; i++) t[i][tid] = hn[(n0 + i) * 256 + tid];
    __syncthreads();
    int hcol = tid;
    for (int i = 0; i < 64; i += 2) {
        unsigned int val = (unsigned short)t[i][hcol] |
                           ((unsigned int)(unsigned short)t[i + 1][hcol] << 16);
        *reinterpret_cast<unsigned int*>(hnT + hcol * NN + n0 + i) = val;
    }
}

// ---------------- k2: projections (bf16 MFMA) ----------------
__global__ __launch_bounds__(256) void k2_proj(const short* __restrict__ hn,
                                               const short* __restrict__ WTcat,
                                               const float* __restrict__ biascat,
                                               short* __restrict__ kml) {
    int bx = blockIdx.x;
    int mt = bx / 12, nb = bx % 12;
    int m0 = mt * 64, n0 = nb * 64;
    int tid = threadIdx.x, w = tid >> 6, lane = tid & 63, q = lane >> 4, c = lane & 15;
    int mrow = m0 + w * 16;
    f32x4 acc[4] = {{0, 0, 0, 0}, {0, 0, 0, 0}, {0, 0, 0, 0}, {0, 0, 0, 0}};
    for (int k0 = 0; k0 < 256; k0 += 32) {
        bf16x8 af = *(const bf16x8*)(hn + (mrow + c) * 256 + k0 + q * 8);
#pragma unroll
        for (int nt = 0; nt < 4; nt++) {
            bf16x8 bf = *(const bf16x8*)(WTcat + (n0 + nt * 16 + c) * 256 + k0 + q * 8);
            acc[nt] = __builtin_amdgcn_mfma_f32_16x16x32_bf16(af, bf, acc[nt], 0, 0, 0);
        }
    }
#pragma unroll
    for (int nt = 0; nt < 4; nt++) {
        int cp = n0 + nt * 16 + c;
        float bias = biascat[cp];
        int mat = cp >> 8, b = (cp >> 6) & 3, y = cp & 63;
        short* dst = kml + (mat * 4 + b) * (NN * HD);
#pragma unroll
        for (int r = 0; r < 4; r++) {
            int m = mrow + 4 * q + r;
            dst[m * HD + y] = f2bf(acc[nt][r] + bias);
        }
    }
}

// ---------------- k3: fused attention-like core ----------------
__global__ __launch_bounds__(256, 3) void k3_fused(
    const short* __restrict__ kh, const short* __restrict__ muh,
    const short* __restrict__ lsh, const short* __restrict__ hnT,
    const float* __restrict__ eps, const float* __restrict__ diff,
    float* __restrict__ agg, float* __restrict__ denom, float* __restrict__ klsum) {
    __shared__ float eps_s[4][32][20];  // [head][z][x], pad 20 -> conflict-free reads
    __shared__ float diff_s[32][20];
    __shared__ short a_s[4][16][40];    // [wave][x][z], pad 40 -> 16B-aligned b128 reads

    const int tid = threadIdx.x;
    const int w = tid >> 6;     // wave == head
    const int lane = tid & 63;
    const int q = lane >> 4;
    const int c = lane & 15;

    const int xt = blockIdx.x >> 2;   // SP==4
    const int sp = blockIdx.x & 3;
    const int x0 = xt * 16;
    const int zbase = sp * ZCHUNK;

    // Q (kh, pre-scaled) fragments: B-operand of S^T: kh[w][x0+c][q*8+j] (+32)
    const bf16x8 qf0 = *(const bf16x8*)(kh + (w * NN + x0 + c) * HD + q * 8);
    const bf16x8 qf1 = *(const bf16x8*)(kh + (w * NN + x0 + c) * HD + 32 + q * 8);

    f32x4 acc[16];
#pragma unroll
    for (int i = 0; i < 16; i++) acc[i] = (f32x4){0.f, 0.f, 0.f, 0.f};
    float den_acc = 0.f, kl_acc = 0.f;

    for (int it = 0; it < NIT; ++it) {
        const int z0 = zbase + it * ZT;
        __syncthreads();  // protect eps_s/a_s reuse from previous iteration
        // stage eps (float4 = all 4 heads) + diffusion, coalesced
#pragma unroll
        for (int i = 0; i < 2; i++) {
            int p = i * 256 + tid;
            int xx = p >> 5, zz = p & 31;
            int base = (x0 + xx) * NN + z0 + zz;
            float4 e = *(const float4*)(eps + base * 4);
            eps_s[0][zz][xx] = e.x;
            eps_s[1][zz][xx] = e.y;
            eps_s[2][zz][xx] = e.z;
            eps_s[3][zz][xx] = e.w;
            diff_s[zz][xx] = diff[base];
        }
        __syncthreads();

        // S^T = muh/lsh @ kh^T for this head: D[m=z][n=x], two 16-z subtiles
        const short* muw = muh + (w * NN + z0) * HD;
        const short* lsw = lsh + (w * NN + z0) * HD;
        f32x4 smu[2], sls[2];
#pragma unroll
        for (int t = 0; t < 2; t++) {
            bf16x8 a0 = *(const bf16x8*)(muw + (t * 16 + c) * HD + q * 8);
            bf16x8 a1 = *(const bf16x8*)(muw + (t * 16 + c) * HD + 32 + q * 8);
            f32x4 z4 = (f32x4){0.f, 0.f, 0.f, 0.f};
            z4 = __builtin_amdgcn_mfma_f32_16x16x32_bf16(a0, qf0, z4, 0, 0, 0);
            z4 = __builtin_amdgcn_mfma_f32_16x16x32_bf16(a1, qf1, z4, 0, 0, 0);
            smu[t] = z4;
            bf16x8 b0 = *(const bf16x8*)(lsw + (t * 16 + c) * HD + q * 8);
            bf16x8 b1 = *(const bf16x8*)(lsw + (t * 16 + c) * HD + 32 + q * 8);
            f32x4 y4 = (f32x4){0.f, 0.f, 0.f, 0.f};
            y4 = __builtin_amdgcn_mfma_f32_16x16x32_bf16(b0, qf0, y4, 0, 0, 0);
            y4 = __builtin_amdgcn_mfma_f32_16x16x32_bf16(b1, qf1, y4, 0, 0, 0);
            sls[t] = y4;
        }

        // elementwise: sigma=softplus(ls), kl, a=exp(mu+sigma*eps)*diff; lane pos:
        // x = x0 + c (C-layout col), z = z0 + 16t + 4q + r (C-layout row)
#pragma unroll
        for (int t = 0; t < 2; t++) {
            short pk[4];
#pragma unroll
            for (int r = 0; r < 4; r++) {
                int zl = t * 16 + 4 * q + r;
                float mu = smu[t][r];
                float ls = sls[t][r];
                float e = eps_s[w][zl][c];
                float d = diff_s[zl][c];
                float ex = __expf(-fabsf(ls));
                float sg = fmaxf(ls, 0.f) + __logf(1.f + ex);
                float kle = -__logf(sg) + 0.5f * (sg * sg + mu * mu) - 0.5f;
                float sgn = (d > 0.f) ? 1.f : ((d < 0.f) ? -1.f : 0.f);
                kl_acc += sgn * kle;
                float a = __expf(mu + sg * e) * d;
                den_acc += fabsf(a);
                pk[r] = f2bf(a);
            }
            *reinterpret_cast<short4*>(&a_s[w][c][t * 16 + 4 * q]) =
                make_short4(pk[0], pk[1], pk[2], pk[3]);
        }
        __syncthreads();  // a_s write -> read ordering (cross-lane)

        // PV: agg[x][h] += a @ hn ; A-frag = a_s[w][c][q*8..+7] (matches A layout)
        bf16x8 af = *(const bf16x8*)(&a_s[w][c][q * 8]);
#pragma unroll
        for (int nt = 0; nt < 16; nt++) {
            bf16x8 bf = *(const bf16x8*)(hnT + (nt * 16 + c) * NN + z0 + q * 8);
            acc[nt] = __builtin_amdgcn_mfma_f32_16x16x32_bf16(af, bf, acc[nt], 0, 0, 0);
        }
    }

    // denominator: lane's positions all had x = x0 + c; reduce across quads
    den_acc += __shfl_down(den_acc, 32);
    den_acc += __shfl_down(den_acc, 16);
    if (q == 0) atomicAdd(&denom[(x0 + c) * NB + w], den_acc);
    // kl: full-wave reduce
    for (int off = 32; off; off >>= 1) kl_acc += __shfl_xor(kl_acc, off);
    if (lane == 0) atomicAdd(klsum, kl_acc);
    // agg: PV C-layout: row = 4q+r -> x, col = c -> h
#pragma unroll
    for (int nt = 0; nt < 16; nt++)
#pragma unroll
        for (int r = 0; r < 4; r++)
            atomicAdd(&agg[((x0 + 4 * q + r) * NB + w) * HH + nt * 16 + c], acc[nt][r]);
}

// ---------------- k3.5: normalize ----------------
__global__ void k35_norm(const float* __restrict__ agg, const float* __restrict__ denom,
                         short* __restrict__ aggn) {
    int x = blockIdx.x, tid = threadIdx.x;
#pragma unroll
    for (int b = 0; b < 4; b++) {
        float dn = fmaxf(denom[x * 4 + b], 1e-12f);
        int i = (x * 4 + b) * 256 + tid;
        aggn[i] = f2bf(agg[i] / dn);
    }
}

// ---------------- k4: fc_v + elu + residual + kl ----------------
__global__ __launch_bounds__(256) void k4_out(const short* __restrict__ aggn,
                                              const short* __restrict__ WvT,
                                              const float* __restrict__ bv,
                                              const float* __restrict__ h,
                                              const float* __restrict__ klsum,
                                              float* __restrict__ out) {
    int bx = blockIdx.x;
    int mt = bx >> 2, nb = bx & 3;
    int m0 = mt * 64, n0 = nb * 64;
    int tid = threadIdx.x, w = tid >> 6, lane = tid & 63, q = lane >> 4, c = lane & 15;
    int mrow = m0 + w * 16;
    f32x4 acc[4] = {{0, 0, 0, 0}, {0, 0, 0, 0}, {0, 0, 0, 0}, {0, 0, 0, 0}};
    for (int k0 = 0; k0 < 1024; k0 += 32) {
        bf16x8 af = *(const bf16x8*)(aggn + (mrow + c) * 1024 + k0 + q * 8);
#pragma unroll
        for (int nt = 0; nt < 4; nt++) {
            bf16x8 bf = *(const bf16x8*)(WvT + (n0 + nt * 16 + c) * 1024 + k0 + q * 8);
            acc[nt] = __builtin_amdgcn_mfma_f32_16x16x32_bf16(af, bf, acc[nt], 0, 0, 0);
        }
    }
#pragma unroll
    for (int nt = 0; nt < 4; nt++) {
        int col = n0 + nt * 16 + c;
        float bias = bv[col];
#pragma unroll
        for (int r = 0; r < 4; r++) {
            int row = mrow + 4 * q + r;
            float v = acc[nt][r] + bias;
            v = (v > 0.f) ? v : (__expf(v) - 1.f);  // elu
            out[row * 256 + col] = v + h[row * 256 + col];
        }
    }
    if (bx == 0 && tid == 0) out[786432] = klsum[0] * (1.0f / 9437184.0f);
}

extern "C" void kernel_launch(void* const* d_in, const int* in_sizes, int n_in,
                              void* d_out, int out_size, void* d_ws, size_t ws_size,
                              hipStream_t stream) {
    const float* h = (const float*)d_in[0];
    const float* gamma = (const float*)d_in[1];
    const float* beta = (const float*)d_in[2];
    const float* Wk = (const float*)d_in[3];
    const float* bk = (const float*)d_in[4];
    const float* Wmu = (const float*)d_in[5];
    const float* bmu = (const float*)d_in[6];
    const float* Wls = (const float*)d_in[7];
    const float* bls = (const float*)d_in[8];
    const float* Wv = (const float*)d_in[9];
    const float* bv = (const float*)d_in[10];
    const float* diff = (const float*)d_in[11];
    const float* eps = (const float*)d_in[12];
    float* out = (float*)d_out;

    char* ws = (char*)d_ws;
    float* agg = (float*)(ws);                       // 12,582,912 B
    float* denom = (float*)(ws + 12582912);          //     49,152 B
    float* klsum = (float*)(ws + 12632064);          //        256 B
    size_t off = 12632320;
    short* hn = (short*)(ws + off);   off += 1572864;
    short* hnT = (short*)(ws + off);  off += 1572864;
    short* kml = (short*)(ws + off);  off += 4718592;  // [3][4][3072][64]
    short* WTcat = (short*)(ws + off); off += 393216;
    float* biasc = (float*)(ws + off); off += 4096;
    short* WvT = (short*)(ws + off);  off += 524288;
    short* aggn = (short*)(ws + off); off += 6291456;  // total ~27.8 MB

    hipMemsetAsync(agg, 0, 12632320, stream);  // zero agg+denom+klsum

    k0_prep<<<1795, 256, 0, stream>>>(Wk, Wmu, Wls, bk, bmu, bls, Wv, WTcat, biasc, WvT);
    k1_ln<<<3072, 256, 0, stream>>>(h, gamma, beta, hn);
    k1b_tr<<<48, 256, 0, stream>>>(hn, hnT);
    k2_proj<<<576, 256, 0, stream>>>(hn, WTcat, biasc, kml);
    k3_fused<<<768, 256, 0, stream>>>(kml, kml + 4 * NN * HD, kml + 8 * NN * HD, hnT,
                                      eps, diff, agg, denom, klsum);
    k35_norm<<<3072, 256, 0, stream>>>(agg, denom, aggn);
    k4_out<<<192, 256, 0, stream>>>(aggn, WvT, bv, h, klsum, out);
}